// Round 5
// baseline (2706.407 us; speedup 1.0000x reference)
//
#include <hip/hip_runtime.h>
#include <hip/hip_bf16.h>

typedef __hip_bfloat16 bf16;
typedef __attribute__((ext_vector_type(8))) short bf16x8;
typedef __attribute__((ext_vector_type(4))) float f32x4;

#define NSTEP 6
#define NBLK 512

static __device__ __forceinline__ float b2f(bf16 v) { return __bfloat162float(v); }

// dtype-dispatched param load: md==0 -> bf16, md==1 -> float32
static __device__ __forceinline__ float ldp(const void* p, int i, int md) {
    return md ? ((const float*)p)[i] : b2f(((const bf16*)p)[i]);
}
static __device__ __forceinline__ float finz(float v) {
    return (v == v && v * 0.0f == 0.0f) ? v : 0.0f;  // non-finite -> 0
}
static __device__ __forceinline__ unsigned short f2bfu(float v) {
    bf16 h = __float2bfloat16(v);
    return *(unsigned short*)&h;
}

// 8 consecutive bf16 -> 8 floats (one 16B load; works for global and LDS)
static __device__ __forceinline__ void ld_bf8(const bf16* p, float* f) {
    union { uint4 u; unsigned short s[8]; } r;
    r.u = *(const uint4*)p;
#pragma unroll
    for (int j = 0; j < 8; ++j) f[j] = __uint_as_float(((unsigned)r.s[j]) << 16);
}
// dtype-dispatched 8-wide param load (i multiple of 8)
static __device__ __forceinline__ void ldp8(const void* p, int i, int md, float* f) {
    if (md) {
        const float* fp = (const float*)p + i;
        float4 a = *(const float4*)fp, b = *(const float4*)(fp + 4);
        f[0]=a.x; f[1]=a.y; f[2]=a.z; f[3]=a.w; f[4]=b.x; f[5]=b.y; f[6]=b.z; f[7]=b.w;
    } else {
        ld_bf8((const bf16*)p + i, f);
    }
}
// pack 8 floats -> uint4 of bf16 (RNE)
static __device__ __forceinline__ uint4 pk_bf8(const float* f) {
    union { uint4 u; unsigned short s[8]; } r;
#pragma unroll
    for (int j = 0; j < 8; ++j) r.s[j] = f2bfu(f[j]);
    return r.u;
}

// manual grid barrier: sense-reversing (cnt,gen), agent-scope atomics.
// Deadlock-safe because grid(512) == guaranteed capacity (LDS 75456<=80K ->
// 2 blocks/CU hard; VGPR<=128 via launch_bounds -> 16 waves/CU) so all
// blocks are co-resident.
static __device__ __forceinline__ void gsync(int* cnt, int* gen) {
    __syncthreads();
    if (threadIdx.x == 0) {
        __threadfence();
        int g = __hip_atomic_load(gen, __ATOMIC_RELAXED, __HIP_MEMORY_SCOPE_AGENT);
        int arrived = __hip_atomic_fetch_add(cnt, 1, __ATOMIC_ACQ_REL, __HIP_MEMORY_SCOPE_AGENT);
        if (arrived == NBLK - 1) {
            __hip_atomic_store(cnt, 0, __ATOMIC_RELAXED, __HIP_MEMORY_SCOPE_AGENT);
            __hip_atomic_fetch_add(gen, 1, __ATOMIC_RELEASE, __HIP_MEMORY_SCOPE_AGENT);
        } else {
            while (__hip_atomic_load(gen, __ATOMIC_ACQUIRE, __HIP_MEMORY_SCOPE_AGENT) == g)
                __builtin_amdgcn_s_sleep(2);
        }
        __threadfence();
    }
    __syncthreads();
}

// ---------------- prologue kernels ----------------

// flags[0]: masks dtype mode (0 int32, 1 u8, 2 16-bit, 3 f32)
// flags[1]: float-array dtype (0 bf16, 1 f32); zeroes accv (96) + bar (2)
__global__ void k_detect(const uint4* __restrict__ m4,
                         const uint4* __restrict__ x4,
                         int* __restrict__ flags, float* __restrict__ accv,
                         int* __restrict__ bar) {
    __shared__ int s3f, sup, slo, sf32;
    int t = threadIdx.x;
    if (t == 0) { s3f = 0; sup = 0; slo = 0; sf32 = 0; }
    if (t < 96) accv[t] = 0.f;
    if (t < 2) bar[t] = 0;
    __syncthreads();
    int l3f = 0, lup = 0, llo = 0, lf = 0;
    for (int i = t; i < 3072; i += 256) {
        uint4 v = m4[i];
        const unsigned* d = (const unsigned*)&v;
#pragma unroll
        for (int j = 0; j < 4; ++j) {
            unsigned w = d[j];
            unsigned x3f = w ^ 0x3F3F3F3Fu;
            if ((x3f - 0x01010101u) & ~x3f & 0x80808080u) l3f = 1;
            if (w & 0xFFFFFF00u) lup = 1;
            if (w & 0x0000FFFFu) llo = 1;
        }
    }
    for (int i = t; i < 4096; i += 256) {
        uint4 v = x4[i];
        const unsigned* d = (const unsigned*)&v;
#pragma unroll
        for (int j = 0; j < 4; ++j) {
            unsigned bb = (d[j] >> 8) & 0x7Fu;
            if (bb > 0x48u) lf = 1;
        }
    }
    if (l3f) atomicOr(&s3f, 1);
    if (lup) atomicOr(&sup, 1);
    if (llo) atomicOr(&slo, 1);
    if (lf)  atomicOr(&sf32, 1);
    __syncthreads();
    if (t == 0) {
        int mode;
        if (!s3f && !sup) mode = 0;
        else if (!s3f)    mode = 1;
        else if (slo)     mode = 2;
        else              mode = 3;
        flags[0] = mode;
        flags[1] = sf32;
    }
}

// fused prep + fold.
// blocks [0,1536): cast x -> f32 [0,262144) | pack bt1 [262144,335872) |
//                  pack 6 weight mats [335872,393216)
// blocks [1536,2560): LN0-fold tables wsum/bconst (reads fc1w directly,
//                     bf16-rounded inline -> identical numerics to t1 GEMM).
__global__ void k_prepfold(const void* __restrict__ x, float* __restrict__ xout,
                           const void* __restrict__ p0, const void* __restrict__ p1,
                           short* __restrict__ bt1,
                           const void* __restrict__ fa, const void* __restrict__ fb,
                           const void* __restrict__ fc, const void* __restrict__ fd,
                           const void* __restrict__ fe, const void* __restrict__ ff,
                           short* __restrict__ packs,
                           const void* __restrict__ n0w, const void* __restrict__ n0b,
                           float* __restrict__ wsum, float* __restrict__ bconst,
                           const int* __restrict__ mflags) {
    __shared__ short fc1T[128 * 64];   // [j][c], fold blocks only
    int md = mflags[1];
    int t = threadIdx.x;
    if (blockIdx.x < 1536) {
        int i = blockIdx.x * 256 + t;
        if (i < 262144) {
            float f[8];
            ldp8(x, i * 8, md, f);
#pragma unroll
            for (int j = 0; j < 8; ++j) f[j] = finz(f[j]);
            *(float4*)&xout[i * 8]     = make_float4(f[0], f[1], f[2], f[3]);
            *(float4*)&xout[i * 8 + 4] = make_float4(f[4], f[5], f[6], f[7]);
        } else if (i < 335872) {
            int j = i - 262144;
            int o = j / 576, k = j % 576;
            int kk = k >> 6, ii = k & 63;
            float v = (o < 64) ? ldp(p0, o * 576 + ii * 9 + kk, md)
                               : ldp(p1, (o - 64) * 576 + ii * 9 + kk, md);
            bt1[j] = (short)f2bfu(v);
        } else {
            int j = i - 335872;
            float v;
            if      (j < 24576) v = ldp(fa, j, md);
            else if (j < 32768) v = ldp(fb, j - 24576, md);
            else if (j < 45056) v = ldp(fc, j - 32768, md);
            else if (j < 49152) v = ldp(fd, j - 45056, md);
            else if (j < 53248) v = ldp(fe, j - 49152, md);
            else                v = ldp(ff, j - 53248, md);
            packs[j] = (short)f2bfu(v);
        }
    } else {
        int fbk = blockIdx.x - 1536;
        for (int e = t; e < 8192; e += 256) {
            int c2 = e >> 7, j = e & 127;
            fc1T[j * 64 + c2] = (short)f2bfu(ldp(fb, c2 * 128 + j, md));
        }
        __syncthreads();
        int c = t & 63, pl = t >> 6;
        int pos = fbk * 4 + pl;
        float ws = 0.f, bs = 0.f;
        for (int j = 0; j < 128; ++j) {
            float f = b2f(*(const bf16*)&fc1T[j * 64 + c]);
            ws = fmaf(ldp(n0w, pos * 128 + j, md), f, ws);
            bs = fmaf(ldp(n0b, pos * 128 + j, md), f, bs);
        }
        wsum[pos * 64 + c]   = ws;
        bconst[pos * 64 + c] = bs;
    }
}

// ---------------- mega step kernel (regular launch + manual grid sync) ----
// grid 512 (2 blocks/CU guaranteed capacity), 512 threads. LDS union 75456 B.
// Per step: A(perceive, t1 in LDS) -gsync- B(update+qkv, q in LDS, kv->global)
// -gsync- C(attn+ffn, final x->global in place) -gsync-.

__global__ __launch_bounds__(512, 4) void k_steps(
    float* __restrict__ xst, const short* __restrict__ bt1,
    const short* __restrict__ fc0s, const short* __restrict__ fc1s,
    const short* __restrict__ qkvs, const short* __restrict__ outs,
    const short* __restrict__ ff1s, const short* __restrict__ ff2s,
    const void* __restrict__ p0b, const void* __restrict__ p1b,
    const void* __restrict__ fc0b, const void* __restrict__ n0w,
    const float* __restrict__ wsum, const float* __restrict__ bconst,
    const void* __restrict__ mraw, const void* __restrict__ ln1w,
    const void* __restrict__ ln1b, const void* __restrict__ outb,
    const void* __restrict__ ln2w, const void* __restrict__ ln2b,
    const void* __restrict__ ff1b, const void* __restrict__ ff2b,
    const int* __restrict__ mflags, float* __restrict__ accv,
    bf16* __restrict__ kvb, int* __restrict__ bar, void* __restrict__ dout)
{
    // LDS union (75456 B), temporally overlaid:
    //  A: xpad@0(28512) P_s@28512(25600) hd_s@0(17408,late) t1l@54112(17408)
    //     red@71520(128)
    //  B: q_l@0(9216,->C) qo@9216(17408) ys@28512(9216) t1l live
    //  C: Ks@9216(28512) Vs@37728(28512) Ao@66240(9216) q_l live; late:
    //     ts@9216(16640,f32) ys2@25856(9216) hs@35072(9216)
    __shared__ __align__(16) char sm[75456];
    short* xpad = (short*)sm;
    short* P_s  = (short*)(sm + 28512);
    short* hd_s = (short*)sm;
    float* t1l  = (float*)(sm + 54112);    // [64][68] f32
    float* red  = (float*)(sm + 71520);
    short* q_l  = (short*)sm;              // [64][72]
    short* qo   = (short*)(sm + 9216);     // [64][136]
    short* ys   = (short*)(sm + 28512);    // [64][72]
    short* Ks   = (short*)(sm + 9216);     // [3][66][72]
    short* Vs   = (short*)(sm + 37728);
    short* Ao   = (short*)(sm + 66240);    // [64][72]
    float* ts   = (float*)(sm + 9216);     // [64][65] f32
    short* ys2  = (short*)(sm + 25856);    // [64][72]
    short* hs   = (short*)(sm + 35072);    // [64][72]

    int md = mflags[1];
    int mmode = mflags[0];
    int bh = blockIdx.x;
    int b = bh >> 6, h = bh & 63;
    int t = threadIdx.x;
    int og = __builtin_amdgcn_readfirstlane(t >> 6);
    int l = t & 63, nl = l & 15, q = l >> 4;
    int tok = t >> 3, j8 = (t & 7) * 8;
    int idx = ((bh << 6) + tok) * 64 + j8;
    const float invN = 1.f / 524288.f;

    for (int step = 0; step < NSTEP; ++step) {
        // ================= Phase A: perceive =================
        for (int e = t; e < 1536; e += 512) {
            int c8 = e & 7, w = (e >> 3) & 63, r = e >> 9;
            int hr = h - 1 + r; hr = hr < 0 ? -hr : (hr > 63 ? 126 - hr : hr);
            const float* src = xst + ((((b << 6) + hr) << 6) | w) * 64 + c8 * 8;
            float f[8];
            float4 v0 = *(const float4*)src, v1 = *(const float4*)(src + 4);
            f[0]=v0.x; f[1]=v0.y; f[2]=v0.z; f[3]=v0.w; f[4]=v1.x; f[5]=v1.y; f[6]=v1.z; f[7]=v1.w;
            uint4 pv = pk_bf8(f);
            *(uint4*)&xpad[((r * 66) + w + 1) * 72 + c8 * 8] = pv;
            if (r == 1) *(uint4*)&P_s[w * 200 + c8 * 8] = pv;
        }
        if (t < 48) {
            int c8 = t & 7, side = (t >> 3) & 1, r = t >> 4;
            int hr = h - 1 + r; hr = hr < 0 ? -hr : (hr > 63 ? 126 - hr : hr);
            int wsrc = side ? 62 : 1, wp = side ? 65 : 0;
            const float* src = xst + ((((b << 6) + hr) << 6) | wsrc) * 64 + c8 * 8;
            float f[8];
            float4 v0 = *(const float4*)src, v1 = *(const float4*)(src + 4);
            f[0]=v0.x; f[1]=v0.y; f[2]=v0.z; f[3]=v0.w; f[4]=v1.x; f[5]=v1.y; f[6]=v1.z; f[7]=v1.w;
            *(uint4*)&xpad[((r * 66) + wp) * 72 + c8 * 8] = pk_bf8(f);
        }
        __syncthreads();

        {
            int mt0 = (og & 1) * 2;
            int nt0 = (og >> 1) * 2;
            int o0  = nt0 * 16 + nl, o1 = o0 + 16;

            f32x4 acc[2][2];
#pragma unroll
            for (int i = 0; i < 2; ++i)
#pragma unroll
                for (int j = 0; j < 2; ++j) acc[i][j] = (f32x4){0.f, 0.f, 0.f, 0.f};

            for (int kt = 0; kt < 18; ++kt) {
                int kk = kt >> 1, c0i = (kt & 1) << 5;
                int r = kk / 3, cxi = kk - r * 3;
                bf16x8 b0 = *(const bf16x8*)(bt1 + o0 * 576 + kt * 32 + q * 8);
                bf16x8 b1 = *(const bf16x8*)(bt1 + o1 * 576 + kt * 32 + q * 8);
                bf16x8 a0 = *(const bf16x8*)&xpad[((r * 66) + mt0 * 16 + nl + cxi) * 72 + c0i + q * 8];
                bf16x8 a1 = *(const bf16x8*)&xpad[((r * 66) + mt0 * 16 + 16 + nl + cxi) * 72 + c0i + q * 8];
                acc[0][0] = __builtin_amdgcn_mfma_f32_16x16x32_bf16(a0, b0, acc[0][0], 0, 0, 0);
                acc[0][1] = __builtin_amdgcn_mfma_f32_16x16x32_bf16(a0, b1, acc[0][1], 0, 0, 0);
                acc[1][0] = __builtin_amdgcn_mfma_f32_16x16x32_bf16(a1, b0, acc[1][0], 0, 0, 0);
                acc[1][1] = __builtin_amdgcn_mfma_f32_16x16x32_bf16(a1, b1, acc[1][1], 0, 0, 0);
            }
            {
                float bias0 = (o0 < 64) ? ldp(p0b, o0, md) : ldp(p1b, o0 - 64, md);
                float bias1 = (o1 < 64) ? ldp(p0b, o1, md) : ldp(p1b, o1 - 64, md);
#pragma unroll
                for (int i = 0; i < 2; ++i)
#pragma unroll
                    for (int j = 0; j < 2; ++j) {
                        int oo = j ? o1 : o0;
                        float bb = j ? bias1 : bias0;
#pragma unroll
                        for (int r2 = 0; r2 < 4; ++r2) {
                            int m = (mt0 + i) * 16 + q * 4 + r2;
                            P_s[m * 200 + 64 + oo] = (short)f2bfu(acc[i][j][r2] + bb);
                        }
                    }
            }
            __syncthreads();

#pragma unroll
            for (int i = 0; i < 2; ++i)
#pragma unroll
                for (int j = 0; j < 2; ++j) acc[i][j] = (f32x4){0.f, 0.f, 0.f, 0.f};
            for (int kt = 0; kt < 6; ++kt) {
                bf16x8 b0 = *(const bf16x8*)(fc0s + o0 * 192 + kt * 32 + q * 8);
                bf16x8 b1 = *(const bf16x8*)(fc0s + o1 * 192 + kt * 32 + q * 8);
                bf16x8 a0 = *(const bf16x8*)&P_s[(mt0 * 16 + nl) * 200 + kt * 32 + q * 8];
                bf16x8 a1 = *(const bf16x8*)&P_s[(mt0 * 16 + 16 + nl) * 200 + kt * 32 + q * 8];
                acc[0][0] = __builtin_amdgcn_mfma_f32_16x16x32_bf16(a0, b0, acc[0][0], 0, 0, 0);
                acc[0][1] = __builtin_amdgcn_mfma_f32_16x16x32_bf16(a0, b1, acc[0][1], 0, 0, 0);
                acc[1][0] = __builtin_amdgcn_mfma_f32_16x16x32_bf16(a1, b0, acc[1][0], 0, 0, 0);
                acc[1][1] = __builtin_amdgcn_mfma_f32_16x16x32_bf16(a1, b1, acc[1][1], 0, 0, 0);
            }
            float lsum = 0.f, lsq = 0.f;
            {
                float fb0 = ldp(fc0b, o0, md), fb1 = ldp(fc0b, o1, md);
#pragma unroll
                for (int i = 0; i < 2; ++i)
#pragma unroll
                    for (int j = 0; j < 2; ++j) {
                        int oo = j ? o1 : o0;
                        float bb = j ? fb1 : fb0;
#pragma unroll
                        for (int r2 = 0; r2 < 4; ++r2) {
                            int m = (mt0 + i) * 16 + q * 4 + r2;
                            float v = fmaxf(acc[i][j][r2] + bb, 0.f);
                            unsigned short hu = f2bfu(v);
                            hd_s[m * 136 + oo] = (short)hu;
                            float vr = __uint_as_float(((unsigned)hu) << 16);
                            lsum += vr; lsq += vr * vr;
                        }
                    }
            }
#pragma unroll
            for (int off = 32; off > 0; off >>= 1) {
                lsum += __shfl_down(lsum, off, 64);
                lsq  += __shfl_down(lsq,  off, 64);
            }
            if (l == 0) { red[og] = lsum; red[16 + og] = lsq; }
            __syncthreads();    // hd_s complete + red complete
            if (t == 0) {
                float a = 0.f, s2 = 0.f;
#pragma unroll
                for (int w = 0; w < 8; ++w) { a += red[w]; s2 += red[16 + w]; }
                atomicAdd(&accv[step * 16 + b * 2],     a);
                atomicAdd(&accv[step * 16 + b * 2 + 1], s2);
            }

            // hdw pass: hd_s *= n0w (positional)
            for (int e = t; e < 1024; e += 512) {
                int pos = e >> 4, jj8 = (e & 15) * 8;
                float hv[8], wv[8];
                ld_bf8((const bf16*)&hd_s[pos * 136 + jj8], hv);
                ldp8(n0w, (h * 64 + pos) * 128 + jj8, md, wv);
#pragma unroll
                for (int j = 0; j < 8; ++j) hv[j] *= wv[j];
                *(uint4*)&hd_s[pos * 136 + jj8] = pk_bf8(hv);
            }
            __syncthreads();

            // t1 GEMM 64x64x128 -> t1l (LDS)
            {
                int mt = og & 3, nh = og >> 2;
                int to0 = nh * 32 + nl, to1 = to0 + 16;
                f32x4 a0 = (f32x4){0.f,0.f,0.f,0.f}, a1 = (f32x4){0.f,0.f,0.f,0.f};
#pragma unroll
                for (int kt = 0; kt < 4; ++kt) {
                    bf16x8 av = *(const bf16x8*)&hd_s[(mt * 16 + nl) * 136 + kt * 32 + q * 8];
                    bf16x8 b0 = *(const bf16x8*)(fc1s + to0 * 128 + kt * 32 + q * 8);
                    bf16x8 b1 = *(const bf16x8*)(fc1s + to1 * 128 + kt * 32 + q * 8);
                    a0 = __builtin_amdgcn_mfma_f32_16x16x32_bf16(av, b0, a0, 0, 0, 0);
                    a1 = __builtin_amdgcn_mfma_f32_16x16x32_bf16(av, b1, a1, 0, 0, 0);
                }
#pragma unroll
                for (int r2 = 0; r2 < 4; ++r2) {
                    int m = mt * 16 + q * 4 + r2;
                    t1l[m * 68 + to0] = a0[r2];
                    t1l[m * 68 + to1] = a1[r2];
                }
            }
        }
        gsync(bar, bar + 1);

        // ================= Phase B: update + LN1 + qkv =================
        float xn8[8], c0;
        {
            float mean = accv[step * 16 + b * 2] * invN;
            float var  = accv[step * 16 + b * 2 + 1] * invN - mean * mean;
            float rstd = rsqrtf(fmaxf(var, 0.f) + 1e-5f);
            float mrs  = mean * rstd;

            float4 x0 = *(const float4*)&xst[idx], x1 = *(const float4*)&xst[idx + 4];
            float xv[8] = {x0.x, x0.y, x0.z, x0.w, x1.x, x1.y, x1.z, x1.w};
            c0 = xv[0];
            float4 a0 = *(const float4*)&t1l[tok * 68 + j8];
            float4 a1 = *(const float4*)&t1l[tok * 68 + j8 + 4];
            float tv[8] = {a0.x, a0.y, a0.z, a0.w, a1.x, a1.y, a1.z, a1.w};
            int ppos = (h * 64 + tok) * 64 + j8;
            float4 w0 = *(const float4*)&wsum[ppos], w1 = *(const float4*)&wsum[ppos + 4];
            float wv[8] = {w0.x, w0.y, w0.z, w0.w, w1.x, w1.y, w1.z, w1.w};
            float4 b0 = *(const float4*)&bconst[ppos], b1 = *(const float4*)&bconst[ppos + 4];
            float bc[8] = {b0.x, b0.y, b0.z, b0.w, b1.x, b1.y, b1.z, b1.w};

            int midx = ((step * 8 + b) * 64 + h) * 64 + tok;
            int mk;
            if (mmode == 0)      mk = ((const int*)mraw)[midx] != 0;
            else if (mmode == 1) mk = ((const unsigned char*)mraw)[midx] != 0;
            else if (mmode == 2) mk = ((const unsigned short*)mraw)[midx] != 0;
            else                 mk = ((const float*)mraw)[midx] != 0.0f;

            float ls = 0.f, lq = 0.f;
#pragma unroll
            for (int ci = 0; ci < 8; ++ci) {
                float dx = rstd * tv[ci] - mrs * wv[ci] + bc[ci];
                xn8[ci] = finz(mk ? (xv[ci] + dx) : xv[ci]);
                ls += xn8[ci]; lq += xn8[ci] * xn8[ci];
            }
#pragma unroll
            for (int off = 1; off < 8; off <<= 1) {
                ls += __shfl_xor(ls, off, 64);
                lq += __shfl_xor(lq, off, 64);
            }
            float mu = ls * (1.f / 64.f);
            float vr = lq * (1.f / 64.f) - mu * mu;
            float rs = rsqrtf(fmaxf(vr, 0.f) + 1e-5f);
            float lw[8], lb[8];
            ldp8(ln1w, j8, md, lw);
            ldp8(ln1b, j8, md, lb);
            float yv[8];
#pragma unroll
            for (int ci = 0; ci < 8; ++ci)
                yv[ci] = (xn8[ci] - mu) * rs * lw[ci] + lb[ci];
            *(uint4*)&ys[tok * 72 + j8] = pk_bf8(yv);
        }
        __syncthreads();

        // qkv GEMM 64x192x64: q -> q_l, k/v -> qo
        {
            int mt = og & 3, nh2 = og >> 2;
            f32x4 qa[6];
#pragma unroll
            for (int n = 0; n < 6; ++n) qa[n] = (f32x4){0.f, 0.f, 0.f, 0.f};
#pragma unroll
            for (int kt = 0; kt < 2; ++kt) {
                bf16x8 av = *(const bf16x8*)&ys[(mt * 16 + nl) * 72 + kt * 32 + q * 8];
#pragma unroll
                for (int n = 0; n < 6; ++n) {
                    bf16x8 bv = *(const bf16x8*)(qkvs + (((nh2 * 6 + n) * 16) + nl) * 64 + kt * 32 + q * 8);
                    qa[n] = __builtin_amdgcn_mfma_f32_16x16x32_bf16(av, bv, qa[n], 0, 0, 0);
                }
            }
#pragma unroll
            for (int n = 0; n < 6; ++n) {
                int nt = nh2 * 6 + n;
#pragma unroll
                for (int r2 = 0; r2 < 4; ++r2) {
                    int m = mt * 16 + q * 4 + r2;
                    short hv = (short)f2bfu(qa[n][r2]);
                    if (nt < 4)      q_l[m * 72 + nt * 16 + nl] = hv;
                    else if (nt < 8) qo[m * 136 + (nt - 4) * 16 + nl] = hv;
                    else             qo[m * 136 + 64 + (nt - 8) * 16 + nl] = hv;
                }
            }
        }
        __syncthreads();
        // kv -> global (vectorized)
        for (int e = t; e < 1024; e += 512) {
            int p2 = e >> 4, c8 = e & 15;
            *(uint4*)(kvb + ((bh << 6) + p2) * 128 + c8 * 8) =
                *(const uint4*)&qo[p2 * 136 + c8 * 8];
        }
        gsync(bar, bar + 1);

        // ================= Phase C: attention + out-proj + MLP =================
        // halo zero
        if (t < 96) {
            int kind = (t >= 48) ? 1 : 0, u = t - kind * 48;
            int r = u >> 4, side = (u >> 3) & 1, c8 = u & 7;
            short* dst = kind ? Vs : Ks;
            uint4 z = {0, 0, 0, 0};
            *(uint4*)&dst[((r * 66) + (side ? 65 : 0)) * 72 + c8 * 8] = z;
        }
        for (int e = t; e < 3072; e += 512) {
            int kind = (e >= 1536) ? 1 : 0, u = e - kind * 1536;
            int c8 = u & 7, w = (u >> 3) & 63, r = u >> 9;
            int hr = h - 1 + r;
            uint4 v = {0, 0, 0, 0};
            if (hr >= 0 && hr <= 63)
                v = *(const uint4*)(kvb + ((b * 64 + hr) * 64 + w) * 128 + kind * 64 + c8 * 8);
            short* dst = kind ? Vs : Ks;
            *(uint4*)&dst[((r * 66) + w + 1) * 72 + c8 * 8] = v;
        }
        __syncthreads();

        {
            int head = __builtin_amdgcn_readfirstlane(t >> 6) & 3;
            int pos  = t & 63;
            bool act = t < 256;
            if (act) {
                float qv[16];
                ld_bf8((const bf16*)&q_l[pos * 72 + head * 16], qv);
                ld_bf8((const bf16*)&q_l[pos * 72 + head * 16 + 8], qv + 8);

                float a9[9];
#pragma unroll
                for (int r = 0; r < 3; ++r)
#pragma unroll
                    for (int cxi = 0; cxi < 3; ++cxi) {
                        const short* kp = &Ks[((r * 66) + pos + cxi) * 72 + head * 16];
                        float kf[16];
                        ld_bf8((const bf16*)kp, kf);
                        ld_bf8((const bf16*)(kp + 8), kf + 8);
                        float dot = 0.f;
#pragma unroll
                        for (int d = 0; d < 16; ++d) dot = fmaf(qv[d], kf[d], dot);
                        a9[r * 3 + cxi] = dot * 0.25f;
                    }
                float mx = a9[0];
#pragma unroll
                for (int k = 1; k < 9; ++k) mx = fmaxf(mx, a9[k]);
                float ssum = 0.f;
#pragma unroll
                for (int k = 0; k < 9; ++k) { a9[k] = __expf(a9[k] - mx); ssum += a9[k]; }
                float inv = 1.f / ssum;
#pragma unroll
                for (int k = 0; k < 9; ++k) a9[k] *= inv;

                float o[16];
#pragma unroll
                for (int d = 0; d < 16; ++d) o[d] = 0.f;
#pragma unroll
                for (int r = 0; r < 3; ++r)
#pragma unroll
                    for (int cxi = 0; cxi < 3; ++cxi) {
                        const short* vp = &Vs[((r * 66) + pos + cxi) * 72 + head * 16];
                        float vf[16];
                        ld_bf8((const bf16*)vp, vf);
                        ld_bf8((const bf16*)(vp + 8), vf + 8);
                        float w = a9[r * 3 + cxi];
#pragma unroll
                        for (int d = 0; d < 16; ++d) o[d] = fmaf(w, vf[d], o[d]);
                    }
                *(uint4*)&Ao[pos * 72 + head * 16]     = pk_bf8(o);
                *(uint4*)&Ao[pos * 72 + head * 16 + 8] = pk_bf8(o + 8);
            }
        }
        __syncthreads();   // Ao visible; Ks/Vs dead beyond this point

        {
            int mt = og & 3;
            int nt0 = (og >> 2) * 2;
            int o0 = nt0 * 16 + nl, o1 = o0 + 16;

            // out-proj -> ts (+bias)
            {
                f32x4 pa[2];
                pa[0] = (f32x4){0.f,0.f,0.f,0.f}; pa[1] = (f32x4){0.f,0.f,0.f,0.f};
#pragma unroll
                for (int kt = 0; kt < 2; ++kt) {
                    bf16x8 av = *(const bf16x8*)&Ao[(mt * 16 + nl) * 72 + kt * 32 + q * 8];
                    bf16x8 b0 = *(const bf16x8*)(outs + o0 * 64 + kt * 32 + q * 8);
                    bf16x8 b1 = *(const bf16x8*)(outs + o1 * 64 + kt * 32 + q * 8);
                    pa[0] = __builtin_amdgcn_mfma_f32_16x16x32_bf16(av, b0, pa[0], 0, 0, 0);
                    pa[1] = __builtin_amdgcn_mfma_f32_16x16x32_bf16(av, b1, pa[1], 0, 0, 0);
                }
                float ob0 = ldp(outb, o0, md), ob1 = ldp(outb, o1, md);
#pragma unroll
                for (int j = 0; j < 2; ++j)
#pragma unroll
                    for (int r2 = 0; r2 < 4; ++r2) {
                        int m = mt * 16 + q * 4 + r2;
                        ts[m * 65 + (j ? o1 : o0)] = pa[j][r2] + (j ? ob1 : ob0);
                    }
            }
            __syncthreads();

            // residual (xn8 regs) + ln2 -> ys2 (ts updated)
            {
                float v[8];
                float ls = 0.f, lq = 0.f;
#pragma unroll
                for (int ci = 0; ci < 8; ++ci) {
                    v[ci] = ts[tok * 65 + j8 + ci] + xn8[ci];
                    ts[tok * 65 + j8 + ci] = v[ci];
                    ls += v[ci]; lq += v[ci] * v[ci];
                }
#pragma unroll
                for (int off = 1; off < 8; off <<= 1) {
                    ls += __shfl_xor(ls, off, 64);
                    lq += __shfl_xor(lq, off, 64);
                }
                float mu = ls * (1.f / 64.f);
                float vr = lq * (1.f / 64.f) - mu * mu;
                float rs = rsqrtf(fmaxf(vr, 0.f) + 1e-5f);
                float wv[8], bv[8];
                ldp8(ln2w, j8, md, wv);
                ldp8(ln2b, j8, md, bv);
                float yv[8];
#pragma unroll
                for (int ci = 0; ci < 8; ++ci) yv[ci] = (v[ci] - mu) * rs * wv[ci] + bv[ci];
                *(uint4*)&ys2[tok * 72 + j8] = pk_bf8(yv);
            }
            __syncthreads();

            // MLP1 + exact GELU -> hs
            {
                f32x4 ma[2];
                ma[0] = (f32x4){0.f,0.f,0.f,0.f}; ma[1] = (f32x4){0.f,0.f,0.f,0.f};
#pragma unroll
                for (int kt = 0; kt < 2; ++kt) {
                    bf16x8 av = *(const bf16x8*)&ys2[(mt * 16 + nl) * 72 + kt * 32 + q * 8];
                    bf16x8 b0 = *(const bf16x8*)(ff1s + o0 * 64 + kt * 32 + q * 8);
                    bf16x8 b1 = *(const bf16x8*)(ff1s + o1 * 64 + kt * 32 + q * 8);
                    ma[0] = __builtin_amdgcn_mfma_f32_16x16x32_bf16(av, b0, ma[0], 0, 0, 0);
                    ma[1] = __builtin_amdgcn_mfma_f32_16x16x32_bf16(av, b1, ma[1], 0, 0, 0);
                }
                float f1b0 = ldp(ff1b, o0, md), f1b1 = ldp(ff1b, o1, md);
#pragma unroll
                for (int j = 0; j < 2; ++j)
#pragma unroll
                    for (int r2 = 0; r2 < 4; ++r2) {
                        int m = mt * 16 + q * 4 + r2;
                        float v = ma[j][r2] + (j ? f1b1 : f1b0);
                        float g = 0.5f * v * (1.f + erff(v * 0.70710678118654752f));
                        hs[m * 72 + (j ? o1 : o0)] = (short)f2bfu(g);
                    }
            }
            __syncthreads();

            // MLP2 + residual into ts
            {
                f32x4 fa[2];
                fa[0] = (f32x4){0.f,0.f,0.f,0.f}; fa[1] = (f32x4){0.f,0.f,0.f,0.f};
#pragma unroll
                for (int kt = 0; kt < 2; ++kt) {
                    bf16x8 av = *(const bf16x8*)&hs[(mt * 16 + nl) * 72 + kt * 32 + q * 8];
                    bf16x8 b0 = *(const bf16x8*)(ff2s + o0 * 64 + kt * 32 + q * 8);
                    bf16x8 b1 = *(const bf16x8*)(ff2s + o1 * 64 + kt * 32 + q * 8);
                    fa[0] = __builtin_amdgcn_mfma_f32_16x16x32_bf16(av, b0, fa[0], 0, 0, 0);
                    fa[1] = __builtin_amdgcn_mfma_f32_16x16x32_bf16(av, b1, fa[1], 0, 0, 0);
                }
                float f2b0 = ldp(ff2b, o0, md), f2b1 = ldp(ff2b, o1, md);
#pragma unroll
                for (int j = 0; j < 2; ++j)
#pragma unroll
                    for (int r2 = 0; r2 < 4; ++r2) {
                        int m = mt * 16 + q * 4 + r2;
                        int oo = j ? o1 : o0;
                        ts[m * 65 + oo] += fa[j][r2] + (j ? f2b1 : f2b0);
                    }
            }
            __syncthreads();

            // final write: ch0 restore + state (in place) + optional out
            {
                float fv[8];
#pragma unroll
                for (int ci = 0; ci < 8; ++ci) {
                    float v = ts[tok * 65 + j8 + ci];
                    if (j8 == 0 && ci == 0) v = c0;
                    fv[ci] = finz(v);
                }
                *(float4*)&xst[idx]     = make_float4(fv[0], fv[1], fv[2], fv[3]);
                *(float4*)&xst[idx + 4] = make_float4(fv[4], fv[5], fv[6], fv[7]);
                if (step == NSTEP - 1) {
                    if (md) {
                        *(float4*)&((float*)dout)[idx]     = make_float4(fv[0], fv[1], fv[2], fv[3]);
                        *(float4*)&((float*)dout)[idx + 4] = make_float4(fv[4], fv[5], fv[6], fv[7]);
                    } else {
                        *(uint4*)&((bf16*)dout)[idx] = pk_bf8(fv);
                    }
                }
            }
        }
        if (step != NSTEP - 1) gsync(bar, bar + 1);
    }
}

// ---------------- launch ----------------

extern "C" void kernel_launch(void* const* d_in, const int* in_sizes, int n_in,
                              void* d_out, int out_size, void* d_ws, size_t ws_size,
                              hipStream_t stream) {
    (void)in_sizes; (void)n_in; (void)out_size; (void)ws_size;
    const void* x     = d_in[0];
    const void* masks = d_in[1];
    const void* p0w   = d_in[2];
    const void* p0b   = d_in[3];
    const void* p1w   = d_in[4];
    const void* p1b   = d_in[5];
    const void* fc0w  = d_in[6];
    const void* fc0b  = d_in[7];
    const void* fc1w  = d_in[8];
    const void* n0w   = d_in[9];
    const void* n0b   = d_in[10];
    const void* ln1w  = d_in[11];
    const void* ln1b  = d_in[12];
    const void* qkvw  = d_in[13];
    const void* outw  = d_in[14];
    const void* outb  = d_in[15];
    const void* ln2w  = d_in[16];
    const void* ln2b  = d_in[17];
    const void* ff1w  = d_in[18];
    const void* ff1b  = d_in[19];
    const void* ff2w  = d_in[20];
    const void* ff2b  = d_in[21];

    // workspace layout ~19.1 MB
    char* wsb = (char*)d_ws;
    float* xst    = (float*)(wsb + 0);           // 8,388,608 B
    bf16*  kvb    = (bf16*) (wsb + 8388608);     // 8,388,608 B
    short* bt1    = (short*)(wsb + 16777216);    //   147,456 B
    short* packs  = (short*)(wsb + 16924672);    //   114,688 B
    float* wsumb  = (float*)(wsb + 17039360);    // 1,048,576 B
    float* bconb  = (float*)(wsb + 18087936);    // 1,048,576 B
    float* accv   = (float*)(wsb + 19136512);    //       384 B
    int*   mflags = (int*)  (wsb + 19136896);    //        16 B
    int*   bar    = (int*)  (wsb + 19136960);    //        64 B (cnt, gen)

    short* fc0s = packs;            // 24576 bf16 [128][192]
    short* fc1s = packs + 24576;    //  8192 bf16 [64][128]
    short* qkvs = packs + 32768;    // 12288 bf16 [192][64]
    short* outs = packs + 45056;    //  4096 bf16 [64][64]
    short* ff1s = packs + 49152;    //  4096
    short* ff2s = packs + 53248;    //  4096

    k_detect<<<1, 256, 0, stream>>>((const uint4*)masks, (const uint4*)x,
                                    mflags, accv, bar);
    k_prepfold<<<2560, 256, 0, stream>>>(x, xst, p0w, p1w, bt1,
                                         fc0w, fc1w, qkvw, outw, ff1w, ff2w,
                                         packs, n0w, n0b, wsumb, bconb, mflags);
    k_steps<<<NBLK, 512, 0, stream>>>(xst, bt1, fc0s, fc1s, qkvs, outs, ff1s, ff2s,
                                      p0b, p1b, fc0b, n0w, wsumb, bconb, masks,
                                      ln1w, ln1b, outb, ln2w, ln2b, ff1b, ff2b,
                                      mflags, accv, kvb, bar, d_out);
}

// Round 6
// 566.058 us; speedup vs baseline: 4.7812x; 4.7812x over previous
//
#include <hip/hip_runtime.h>
#include <hip/hip_bf16.h>

typedef __hip_bfloat16 bf16;
typedef __attribute__((ext_vector_type(8))) short bf16x8;
typedef __attribute__((ext_vector_type(4))) float f32x4;

#define NSTEP 6

static __device__ __forceinline__ float b2f(bf16 v) { return __bfloat162float(v); }

// dtype-dispatched param load: md==0 -> bf16, md==1 -> float32
static __device__ __forceinline__ float ldp(const void* p, int i, int md) {
    return md ? ((const float*)p)[i] : b2f(((const bf16*)p)[i]);
}
static __device__ __forceinline__ float finz(float v) {
    return (v == v && v * 0.0f == 0.0f) ? v : 0.0f;  // non-finite -> 0
}
static __device__ __forceinline__ unsigned short f2bfu(float v) {
    bf16 h = __float2bfloat16(v);
    return *(unsigned short*)&h;
}

// 8 consecutive bf16 -> 8 floats (one 16B load; works for global and LDS)
static __device__ __forceinline__ void ld_bf8(const bf16* p, float* f) {
    union { uint4 u; unsigned short s[8]; } r;
    r.u = *(const uint4*)p;
#pragma unroll
    for (int j = 0; j < 8; ++j) f[j] = __uint_as_float(((unsigned)r.s[j]) << 16);
}
// dtype-dispatched 8-wide param load (i multiple of 8)
static __device__ __forceinline__ void ldp8(const void* p, int i, int md, float* f) {
    if (md) {
        const float* fp = (const float*)p + i;
        float4 a = *(const float4*)fp, b = *(const float4*)(fp + 4);
        f[0]=a.x; f[1]=a.y; f[2]=a.z; f[3]=a.w; f[4]=b.x; f[5]=b.y; f[6]=b.z; f[7]=b.w;
    } else {
        ld_bf8((const bf16*)p + i, f);
    }
}
// pack 8 floats -> uint4 of bf16 (RNE)
static __device__ __forceinline__ uint4 pk_bf8(const float* f) {
    union { uint4 u; unsigned short s[8]; } r;
#pragma unroll
    for (int j = 0; j < 8; ++j) r.s[j] = f2bfu(f[j]);
    return r.u;
}

// ---------------- prologue kernels ----------------

// flags[0]: masks dtype mode (0 int32, 1 u8, 2 16-bit, 3 f32)
// flags[1]: float-array dtype (0 bf16, 1 f32); also zeroes accv (96 floats)
__global__ void k_detect(const uint4* __restrict__ m4,
                         const uint4* __restrict__ x4,
                         int* __restrict__ flags, float* __restrict__ accv) {
    __shared__ int s3f, sup, slo, sf32;
    int t = threadIdx.x;
    if (t == 0) { s3f = 0; sup = 0; slo = 0; sf32 = 0; }
    if (t < 96) accv[t] = 0.f;
    __syncthreads();
    int l3f = 0, lup = 0, llo = 0, lf = 0;
    for (int i = t; i < 3072; i += 256) {
        uint4 v = m4[i];
        const unsigned* d = (const unsigned*)&v;
#pragma unroll
        for (int j = 0; j < 4; ++j) {
            unsigned w = d[j];
            unsigned x3f = w ^ 0x3F3F3F3Fu;
            if ((x3f - 0x01010101u) & ~x3f & 0x80808080u) l3f = 1;
            if (w & 0xFFFFFF00u) lup = 1;
            if (w & 0x0000FFFFu) llo = 1;
        }
    }
    for (int i = t; i < 4096; i += 256) {
        uint4 v = x4[i];
        const unsigned* d = (const unsigned*)&v;
#pragma unroll
        for (int j = 0; j < 4; ++j) {
            unsigned bb = (d[j] >> 8) & 0x7Fu;
            if (bb > 0x48u) lf = 1;
        }
    }
    if (l3f) atomicOr(&s3f, 1);
    if (lup) atomicOr(&sup, 1);
    if (llo) atomicOr(&slo, 1);
    if (lf)  atomicOr(&sf32, 1);
    __syncthreads();
    if (t == 0) {
        int mode;
        if (!s3f && !sup) mode = 0;
        else if (!s3f)    mode = 1;
        else if (slo)     mode = 2;
        else              mode = 3;
        flags[0] = mode;
        flags[1] = sf32;
    }
}

// fused prep: branch by blockIdx.
//  [0,1024):    cast x -> f32 state
//  [1024,1152): straight bf16 packs (fc1 8192 | qkv 12288 | out/ff1/ff2 4096ea)
//  [1152,1440): cw fold: cw[o][kk*64+i] = sum_c p0w[c,i,kk]*fc0w[o,64+c]
//                + p1w[c,i,kk]*fc0w[o,128+c] + (kk==4)*fc0w[o,i]   (f32 acc)
//  1440:        hbias[o] = fc0b[o] + sum_c p0b[c]*fc0w[o,64+c]+p1b[c]*fc0w[o,128+c]
//  [1441,2465): LN0-fold tables wsum/bconst (fc1 bf16-rounded inline)
__global__ void k_prep(const void* __restrict__ x, float* __restrict__ xout,
                       const void* __restrict__ p0w, const void* __restrict__ p1w,
                       const void* __restrict__ p0b, const void* __restrict__ p1b,
                       const void* __restrict__ fc0w, const void* __restrict__ fc0b,
                       const void* __restrict__ fc1w, const void* __restrict__ qkvw,
                       const void* __restrict__ outw, const void* __restrict__ ff1w,
                       const void* __restrict__ ff2w,
                       short* __restrict__ cw, short* __restrict__ packs,
                       float* __restrict__ hbias,
                       const void* __restrict__ n0w, const void* __restrict__ n0b,
                       float* __restrict__ wsum, float* __restrict__ bconst,
                       const int* __restrict__ mflags) {
    __shared__ short fc1T[128 * 64];   // [j][c], LN0-fold blocks only
    int md = mflags[1];
    int t = threadIdx.x;
    int bk = blockIdx.x;
    if (bk < 1024) {
        int i = bk * 256 + t;
        float f[8];
        ldp8(x, i * 8, md, f);
#pragma unroll
        for (int j = 0; j < 8; ++j) f[j] = finz(f[j]);
        *(float4*)&xout[i * 8]     = make_float4(f[0], f[1], f[2], f[3]);
        *(float4*)&xout[i * 8 + 4] = make_float4(f[4], f[5], f[6], f[7]);
    } else if (bk < 1152) {
        int j = (bk - 1024) * 256 + t;
        float v;
        if      (j < 8192)  v = ldp(fc1w, j, md);
        else if (j < 20480) v = ldp(qkvw, j - 8192, md);
        else if (j < 24576) v = ldp(outw, j - 20480, md);
        else if (j < 28672) v = ldp(ff1w, j - 24576, md);
        else                v = ldp(ff2w, j - 28672, md);
        packs[j] = (short)f2bfu(v);
    } else if (bk < 1440) {
        int p = (bk - 1152) * 4 + (t >> 6);   // (o,kk) pair in [0,1152)
        int i = t & 63;
        int o = p / 9, kk = p - o * 9;
        float acc = (kk == 4) ? ldp(fc0w, o * 192 + i, md) : 0.f;
        for (int c = 0; c < 64; ++c) {
            acc = fmaf(ldp(p0w, c * 576 + i * 9 + kk, md), ldp(fc0w, o * 192 + 64 + c, md), acc);
            acc = fmaf(ldp(p1w, c * 576 + i * 9 + kk, md), ldp(fc0w, o * 192 + 128 + c, md), acc);
        }
        cw[o * 576 + kk * 64 + i] = (short)f2bfu(acc);
    } else if (bk == 1440) {
        if (t < 128) {
            float hb = ldp(fc0b, t, md);
            for (int c = 0; c < 64; ++c) {
                hb = fmaf(ldp(p0b, c, md), ldp(fc0w, t * 192 + 64 + c, md), hb);
                hb = fmaf(ldp(p1b, c, md), ldp(fc0w, t * 192 + 128 + c, md), hb);
            }
            hbias[t] = hb;
        }
    } else {
        int fbk = bk - 1441;
        for (int e = t; e < 8192; e += 256) {
            int c2 = e >> 7, j = e & 127;
            fc1T[j * 64 + c2] = (short)f2bfu(ldp(fc1w, c2 * 128 + j, md));
        }
        __syncthreads();
        int c = t & 63, pl = t >> 6;
        int pos = fbk * 4 + pl;
        float ws = 0.f, bs = 0.f;
        for (int j = 0; j < 128; ++j) {
            float f = b2f(*(const bf16*)&fc1T[j * 64 + c]);
            ws = fmaf(ldp(n0w, pos * 128 + j, md), f, ws);
            bs = fmaf(ldp(n0b, pos * 128 + j, md), f, bs);
        }
        wsum[pos * 64 + c]   = ws;
        bconst[pos * 64 + c] = bs;
    }
}

// ---------------- step kernels ----------------
// grid 512 = B*H rows, 512 threads (8 waves) per block.

// A (MFMA): folded conv+fc0 implicit GEMM [64x128x576] -> hd (LDS) + stats +
// t1 = (hd*n0w) @ fc1^T [64x64x128] -> global. LDS 46048 B.
__global__ __launch_bounds__(512) void k_perceive(
    const float* __restrict__ xin, const short* __restrict__ cw,
    const short* __restrict__ fc1s, const float* __restrict__ hbias,
    const void* __restrict__ n0w, const int* __restrict__ mflags,
    float* __restrict__ t1, float* __restrict__ accv, int step)
{
    __shared__ __align__(16) short xpad_s[3 * 66 * 72];   // 28512
    __shared__ __align__(16) short hd_s[64 * 136];        // 17408
    __shared__ float red[32];
    int md = mflags[1];
    int bh = blockIdx.x;
    int b = bh >> 6, h = bh & 63;
    int t = threadIdx.x;

    for (int e = t; e < 1536; e += 512) {
        int c8 = e & 7, w = (e >> 3) & 63, r = e >> 9;
        int hr = h - 1 + r; hr = hr < 0 ? -hr : (hr > 63 ? 126 - hr : hr);
        const float* src = xin + ((((b << 6) + hr) << 6) | w) * 64 + c8 * 8;
        float f[8];
        float4 v0 = *(const float4*)src, v1 = *(const float4*)(src + 4);
        f[0]=v0.x; f[1]=v0.y; f[2]=v0.z; f[3]=v0.w; f[4]=v1.x; f[5]=v1.y; f[6]=v1.z; f[7]=v1.w;
        *(uint4*)&xpad_s[((r * 66) + w + 1) * 72 + c8 * 8] = pk_bf8(f);
    }
    if (t < 48) {
        int c8 = t & 7, side = (t >> 3) & 1, r = t >> 4;
        int hr = h - 1 + r; hr = hr < 0 ? -hr : (hr > 63 ? 126 - hr : hr);
        int wsrc = side ? 62 : 1, wp = side ? 65 : 0;
        const float* src = xin + ((((b << 6) + hr) << 6) | wsrc) * 64 + c8 * 8;
        float f[8];
        float4 v0 = *(const float4*)src, v1 = *(const float4*)(src + 4);
        f[0]=v0.x; f[1]=v0.y; f[2]=v0.z; f[3]=v0.w; f[4]=v1.x; f[5]=v1.y; f[6]=v1.z; f[7]=v1.w;
        *(uint4*)&xpad_s[((r * 66) + wp) * 72 + c8 * 8] = pk_bf8(f);
    }
    __syncthreads();

    int og  = __builtin_amdgcn_readfirstlane(t >> 6);
    int l   = t & 63, nl = l & 15, q = l >> 4;
    int mt0 = (og & 1) * 2;
    int nt0 = (og >> 1) * 2;
    int o0  = nt0 * 16 + nl, o1 = o0 + 16;

    f32x4 acc[2][2];
#pragma unroll
    for (int i = 0; i < 2; ++i)
#pragma unroll
        for (int j = 0; j < 2; ++j) acc[i][j] = (f32x4){0.f, 0.f, 0.f, 0.f};

    for (int kt = 0; kt < 18; ++kt) {
        int kk = kt >> 1, c0 = (kt & 1) << 5;
        int r = kk / 3, cxi = kk - r * 3;
        bf16x8 b0 = *(const bf16x8*)(cw + o0 * 576 + kt * 32 + q * 8);
        bf16x8 b1 = *(const bf16x8*)(cw + o1 * 576 + kt * 32 + q * 8);
        bf16x8 a0 = *(const bf16x8*)&xpad_s[((r * 66) + mt0 * 16 + nl + cxi) * 72 + c0 + q * 8];
        bf16x8 a1 = *(const bf16x8*)&xpad_s[((r * 66) + mt0 * 16 + 16 + nl + cxi) * 72 + c0 + q * 8];
        acc[0][0] = __builtin_amdgcn_mfma_f32_16x16x32_bf16(a0, b0, acc[0][0], 0, 0, 0);
        acc[0][1] = __builtin_amdgcn_mfma_f32_16x16x32_bf16(a0, b1, acc[0][1], 0, 0, 0);
        acc[1][0] = __builtin_amdgcn_mfma_f32_16x16x32_bf16(a1, b0, acc[1][0], 0, 0, 0);
        acc[1][1] = __builtin_amdgcn_mfma_f32_16x16x32_bf16(a1, b1, acc[1][1], 0, 0, 0);
    }

    float lsum = 0.f, lsq = 0.f;
    {
        float hb0 = hbias[o0], hb1 = hbias[o1];
#pragma unroll
        for (int i = 0; i < 2; ++i)
#pragma unroll
            for (int j = 0; j < 2; ++j) {
                int oo = j ? o1 : o0;
                float bb = j ? hb1 : hb0;
#pragma unroll
                for (int r2 = 0; r2 < 4; ++r2) {
                    int m = (mt0 + i) * 16 + q * 4 + r2;
                    float v = fmaxf(acc[i][j][r2] + bb, 0.f);
                    unsigned short hu = f2bfu(v);
                    hd_s[m * 136 + oo] = (short)hu;
                    float vr = __uint_as_float(((unsigned)hu) << 16);
                    lsum += vr; lsq += vr * vr;
                }
            }
    }
#pragma unroll
    for (int off = 32; off > 0; off >>= 1) {
        lsum += __shfl_down(lsum, off, 64);
        lsq  += __shfl_down(lsq,  off, 64);
    }
    if (l == 0) { red[og] = lsum; red[16 + og] = lsq; }
    __syncthreads();    // hd_s complete + red complete
    if (t == 0) {
        float a = 0.f, s2 = 0.f;
#pragma unroll
        for (int w = 0; w < 8; ++w) { a += red[w]; s2 += red[16 + w]; }
        atomicAdd(&accv[step * 16 + b * 2],     a);
        atomicAdd(&accv[step * 16 + b * 2 + 1], s2);
    }

    // hdw pass: hd_s *= n0w (positional), vectorized
    for (int e = t; e < 1024; e += 512) {
        int pos = e >> 4, j8 = (e & 15) * 8;
        float hv[8], wv[8];
        ld_bf8((const bf16*)&hd_s[pos * 136 + j8], hv);
        ldp8(n0w, (h * 64 + pos) * 128 + j8, md, wv);
#pragma unroll
        for (int j = 0; j < 8; ++j) hv[j] *= wv[j];
        *(uint4*)&hd_s[pos * 136 + j8] = pk_bf8(hv);
    }
    __syncthreads();

    // t1 GEMM 64x64x128: wave og -> M-tile og&3, N-half og>>2
    {
        int mt = og & 3, nh = og >> 2;
        int to0 = nh * 32 + nl, to1 = to0 + 16;
        f32x4 a0 = (f32x4){0.f,0.f,0.f,0.f}, a1 = (f32x4){0.f,0.f,0.f,0.f};
#pragma unroll
        for (int kt = 0; kt < 4; ++kt) {
            bf16x8 av = *(const bf16x8*)&hd_s[(mt * 16 + nl) * 136 + kt * 32 + q * 8];
            bf16x8 b0 = *(const bf16x8*)(fc1s + to0 * 128 + kt * 32 + q * 8);
            bf16x8 b1 = *(const bf16x8*)(fc1s + to1 * 128 + kt * 32 + q * 8);
            a0 = __builtin_amdgcn_mfma_f32_16x16x32_bf16(av, b0, a0, 0, 0, 0);
            a1 = __builtin_amdgcn_mfma_f32_16x16x32_bf16(av, b1, a1, 0, 0, 0);
        }
#pragma unroll
        for (int r2 = 0; r2 < 4; ++r2) {
            int m = mt * 16 + q * 4 + r2;
            t1[((bh << 6) + m) * 64 + to0] = a0[r2];
            t1[((bh << 6) + m) * 64 + to1] = a1[r2];
        }
    }
}

// B (slim): x_new = x + mask*(rstd*t1 - mean*rstd*wsum + bconst) -> xnew;
// LN1 (8-lane shfl) -> ys; qkv GEMM 64x192x64 -> qkv global.
__global__ __launch_bounds__(512) void k_upd(
    const float* __restrict__ xin, float* __restrict__ xnew,
    const float* __restrict__ t1, const float* __restrict__ wsum,
    const float* __restrict__ bconst, const void* __restrict__ mraw,
    const short* __restrict__ qkvs, const void* __restrict__ ln1w,
    const void* __restrict__ ln1b, const int* __restrict__ mflags,
    const float* __restrict__ accv, bf16* __restrict__ qkv, int step)
{
    __shared__ __align__(16) short ys[64 * 72];
    __shared__ __align__(16) short qo[64 * 200];
    int md = mflags[1];
    int bh = blockIdx.x;
    int b = bh >> 6, h = bh & 63;
    int t = threadIdx.x;
    const float invN = 1.f / 524288.f;
    float mean = accv[step * 16 + b * 2] * invN;
    float var  = accv[step * 16 + b * 2 + 1] * invN - mean * mean;
    float rstd = rsqrtf(fmaxf(var, 0.f) + 1e-5f);
    float mrs  = mean * rstd;

    int tok = t >> 3, j8 = (t & 7) * 8;
    int idx = ((bh << 6) + tok) * 64 + j8;
    int ppos = (h * 64 + tok) * 64 + j8;
    {
        float4 x0 = *(const float4*)&xin[idx], x1 = *(const float4*)&xin[idx + 4];
        float xv[8] = {x0.x, x0.y, x0.z, x0.w, x1.x, x1.y, x1.z, x1.w};
        float4 a0 = *(const float4*)&t1[idx], a1 = *(const float4*)&t1[idx + 4];
        float tv[8] = {a0.x, a0.y, a0.z, a0.w, a1.x, a1.y, a1.z, a1.w};
        float4 w0 = *(const float4*)&wsum[ppos], w1 = *(const float4*)&wsum[ppos + 4];
        float wv[8] = {w0.x, w0.y, w0.z, w0.w, w1.x, w1.y, w1.z, w1.w};
        float4 b0 = *(const float4*)&bconst[ppos], b1 = *(const float4*)&bconst[ppos + 4];
        float bc[8] = {b0.x, b0.y, b0.z, b0.w, b1.x, b1.y, b1.z, b1.w};

        int mmode = mflags[0];
        int midx = ((step * 8 + b) * 64 + h) * 64 + tok;
        int mk;
        if (mmode == 0)      mk = ((const int*)mraw)[midx] != 0;
        else if (mmode == 1) mk = ((const unsigned char*)mraw)[midx] != 0;
        else if (mmode == 2) mk = ((const unsigned short*)mraw)[midx] != 0;
        else                 mk = ((const float*)mraw)[midx] != 0.0f;

        float vloc[8];
        float ls = 0.f, lq = 0.f;
#pragma unroll
        for (int ci = 0; ci < 8; ++ci) {
            float dx = rstd * tv[ci] - mrs * wv[ci] + bc[ci];
            vloc[ci] = finz(mk ? (xv[ci] + dx) : xv[ci]);
            ls += vloc[ci]; lq += vloc[ci] * vloc[ci];
        }
        *(float4*)&xnew[idx]     = make_float4(vloc[0], vloc[1], vloc[2], vloc[3]);
        *(float4*)&xnew[idx + 4] = make_float4(vloc[4], vloc[5], vloc[6], vloc[7]);
#pragma unroll
        for (int off = 1; off < 8; off <<= 1) {
            ls += __shfl_xor(ls, off, 64);
            lq += __shfl_xor(lq, off, 64);
        }
        float mu = ls * (1.f / 64.f);
        float vr = lq * (1.f / 64.f) - mu * mu;
        float rs = rsqrtf(fmaxf(vr, 0.f) + 1e-5f);
        float lw[8], lb[8];
        ldp8(ln1w, j8, md, lw);
        ldp8(ln1b, j8, md, lb);
        float yv[8];
#pragma unroll
        for (int ci = 0; ci < 8; ++ci)
            yv[ci] = (vloc[ci] - mu) * rs * lw[ci] + lb[ci];
        *(uint4*)&ys[tok * 72 + j8] = pk_bf8(yv);
    }
    __syncthreads();

    // qkv GEMM 64x192x64: wave og -> M-tile og&3, 6 N-tiles per half
    int og = __builtin_amdgcn_readfirstlane(t >> 6);
    int l = t & 63, nl = l & 15, q = l >> 4;
    {
        int mt = og & 3, nh2 = og >> 2;
        f32x4 qa[6];
#pragma unroll
        for (int n = 0; n < 6; ++n) qa[n] = (f32x4){0.f, 0.f, 0.f, 0.f};
#pragma unroll
        for (int kt = 0; kt < 2; ++kt) {
            bf16x8 av = *(const bf16x8*)&ys[(mt * 16 + nl) * 72 + kt * 32 + q * 8];
#pragma unroll
            for (int n = 0; n < 6; ++n) {
                bf16x8 bv = *(const bf16x8*)(qkvs + (((nh2 * 6 + n) * 16) + nl) * 64 + kt * 32 + q * 8);
                qa[n] = __builtin_amdgcn_mfma_f32_16x16x32_bf16(av, bv, qa[n], 0, 0, 0);
            }
        }
#pragma unroll
        for (int n = 0; n < 6; ++n)
#pragma unroll
            for (int r2 = 0; r2 < 4; ++r2) {
                int m = mt * 16 + q * 4 + r2;
                qo[m * 200 + (nh2 * 6 + n) * 16 + nl] = (short)f2bfu(qa[n][r2]);
            }
    }
    __syncthreads();

    // vectorized qkv store
    for (int e = t; e < 1536; e += 512) {
        int p2 = e / 24, c8 = e - p2 * 24;
        *(uint4*)(qkv + ((bh << 6) + p2) * 192 + c8 * 8) =
            *(const uint4*)&qo[p2 * 200 + c8 * 8];
    }
}

// C: attention (VALU, bf16 LDS, dedup'd) + out-proj/MLP1/MLP2 on MFMA +
// fused residual+ln2. x_new preloaded to registers; ch0 restored from x_old.
__global__ __launch_bounds__(512) void k_attn_ff(
    const bf16* __restrict__ qkv, const float* __restrict__ xold,
    float* __restrict__ xnew, const short* __restrict__ outs,
    const short* __restrict__ ff1s, const short* __restrict__ ff2s,
    const void* __restrict__ outb, const void* __restrict__ ln2w,
    const void* __restrict__ ln2b, const void* __restrict__ ff1b,
    const void* __restrict__ ff2b, const int* __restrict__ mflags,
    void* __restrict__ dout, int write_out)
{
    // Ks [3][66][72] @0 (28512) | Vs @28512 (28512) | Ao [64][72] @57024
    // (9216). overlays after attention (Ks/Vs dead): ts f32 [64][65] @0
    // (16640); ys [64][72] @16640 (9216); hs [64][72] @25856 (9216).
    __shared__ __align__(16) char smraw[66240];
    short* Ks = (short*)smraw;
    short* Vs = (short*)(smraw + 28512);
    short* Ao = (short*)(smraw + 57024);
    float* ts = (float*)smraw;
    short* ys = (short*)(smraw + 16640);
    short* hs = (short*)(smraw + 25856);

    int md = mflags[1];
    int bh = blockIdx.x;
    int b = bh >> 6, h = bh & 63;
    int t = threadIdx.x;
    int tok = t >> 3, j8 = (t & 7) * 8;
    int idx = ((bh << 6) + tok) * 64 + j8;

    // preload own-row x_new (residual input) + x_old ch0
    float xn8[8];
    {
        float4 x0 = *(const float4*)&xnew[idx], x1 = *(const float4*)&xnew[idx + 4];
        xn8[0]=x0.x; xn8[1]=x0.y; xn8[2]=x0.z; xn8[3]=x0.w;
        xn8[4]=x1.x; xn8[5]=x1.y; xn8[6]=x1.z; xn8[7]=x1.w;
    }
    float c0 = (j8 == 0) ? xold[idx] : 0.f;

    // zero halo columns (w=0, w=65) of K and V
    if (t < 96) {
        int kind = (t >= 48) ? 1 : 0, u = t - kind * 48;
        int r = u >> 4, side = (u >> 3) & 1, c8 = u & 7;
        short* dst = kind ? Vs : Ks;
        uint4 z = {0, 0, 0, 0};
        *(uint4*)&dst[((r * 66) + (side ? 65 : 0)) * 72 + c8 * 8] = z;
    }
    // K + V staging: raw bf16 uint4 copies, no conversion
    for (int e = t; e < 3072; e += 512) {
        int kind = (e >= 1536) ? 1 : 0, u = e - kind * 1536;
        int c8 = u & 7, w = (u >> 3) & 63, r = u >> 9;
        int hr = h - 1 + r;
        uint4 v = {0, 0, 0, 0};
        if (hr >= 0 && hr <= 63)
            v = *(const uint4*)(qkv + ((b * 64 + hr) * 64 + w) * 192 + 64 + kind * 64 + c8 * 8);
        short* dst = kind ? Vs : Ks;
        *(uint4*)&dst[((r * 66) + w + 1) * 72 + c8 * 8] = v;
    }
    __syncthreads();

    int head = __builtin_amdgcn_readfirstlane(t >> 6) & 3;
    int pos  = t & 63;
    bool act = t < 256;   // waves 4..7 skip attention (was duplicated work)
    if (act) {
        float qv[16];
        const bf16* qr = qkv + (((b * 64 + h) * 64) + pos) * 192 + head * 16;
        ld_bf8(qr, qv); ld_bf8(qr + 8, qv + 8);

        float a9[9];
#pragma unroll
        for (int r = 0; r < 3; ++r)
#pragma unroll
            for (int cxi = 0; cxi < 3; ++cxi) {
                const short* kp = &Ks[((r * 66) + pos + cxi) * 72 + head * 16];
                float kf[16];
                ld_bf8((const bf16*)kp, kf);
                ld_bf8((const bf16*)(kp + 8), kf + 8);
                float dot = 0.f;
#pragma unroll
                for (int d = 0; d < 16; ++d) dot = fmaf(qv[d], kf[d], dot);
                a9[r * 3 + cxi] = dot * 0.25f;
            }
        float mx = a9[0];
#pragma unroll
        for (int k = 1; k < 9; ++k) mx = fmaxf(mx, a9[k]);
        float ssum = 0.f;
#pragma unroll
        for (int k = 0; k < 9; ++k) { a9[k] = __expf(a9[k] - mx); ssum += a9[k]; }
        float inv = 1.f / ssum;
#pragma unroll
        for (int k = 0; k < 9; ++k) a9[k] *= inv;

        float o[16];
#pragma unroll
        for (int d = 0; d < 16; ++d) o[d] = 0.f;
#pragma unroll
        for (int r = 0; r < 3; ++r)
#pragma unroll
            for (int cxi = 0; cxi < 3; ++cxi) {
                const short* vp = &Vs[((r * 66) + pos + cxi) * 72 + head * 16];
                float vf[16];
                ld_bf8((const bf16*)vp, vf);
                ld_bf8((const bf16*)(vp + 8), vf + 8);
                float w = a9[r * 3 + cxi];
#pragma unroll
                for (int d = 0; d < 16; ++d) o[d] = fmaf(w, vf[d], o[d]);
            }
        // Ao is non-overlapping -> no barrier needed before this write
        *(uint4*)&Ao[pos * 72 + head * 16]     = pk_bf8(o);
        *(uint4*)&Ao[pos * 72 + head * 16 + 8] = pk_bf8(o + 8);
    }
    __syncthreads();   // Ao visible; Ks/Vs dead beyond this point

    // ---- MFMA phases: 64x64x64 GEMMs, wave og: mt = og&3, n-tiles {nt0,nt0+1}
    int og = __builtin_amdgcn_readfirstlane(t >> 6);
    int l = t & 63, nl = l & 15, qd = l >> 4;
    int mt = og & 3;
    int nt0 = (og >> 2) * 2;
    int o0 = nt0 * 16 + nl, o1 = o0 + 16;

    // out-proj -> ts (+bias)
    {
        f32x4 pa[2];
        pa[0] = (f32x4){0.f,0.f,0.f,0.f}; pa[1] = (f32x4){0.f,0.f,0.f,0.f};
#pragma unroll
        for (int kt = 0; kt < 2; ++kt) {
            bf16x8 av = *(const bf16x8*)&Ao[(mt * 16 + nl) * 72 + kt * 32 + qd * 8];
            bf16x8 b0 = *(const bf16x8*)(outs + o0 * 64 + kt * 32 + qd * 8);
            bf16x8 b1 = *(const bf16x8*)(outs + o1 * 64 + kt * 32 + qd * 8);
            pa[0] = __builtin_amdgcn_mfma_f32_16x16x32_bf16(av, b0, pa[0], 0, 0, 0);
            pa[1] = __builtin_amdgcn_mfma_f32_16x16x32_bf16(av, b1, pa[1], 0, 0, 0);
        }
        float ob0 = ldp(outb, o0, md), ob1 = ldp(outb, o1, md);
#pragma unroll
        for (int j = 0; j < 2; ++j)
#pragma unroll
            for (int r2 = 0; r2 < 4; ++r2) {
                int m = mt * 16 + qd * 4 + r2;
                ts[m * 65 + (j ? o1 : o0)] = pa[j][r2] + (j ? ob1 : ob0);
            }
    }
    __syncthreads();

    // residual (x_new from registers) + ln2, fused -> ys bf16 (ts updated)
    {
        float v[8];
        float ls = 0.f, lq = 0.f;
#pragma unroll
        for (int ci = 0; ci < 8; ++ci) {
            v[ci] = ts[tok * 65 + j8 + ci] + xn8[ci];
            ts[tok * 65 + j8 + ci] = v[ci];
            ls += v[ci]; lq += v[ci] * v[ci];
        }
#pragma unroll
        for (int off = 1; off < 8; off <<= 1) {
            ls += __shfl_xor(ls, off, 64);
            lq += __shfl_xor(lq, off, 64);
        }
        float mu = ls * (1.f / 64.f);
        float vr = lq * (1.f / 64.f) - mu * mu;
        float rs = rsqrtf(fmaxf(vr, 0.f) + 1e-5f);
        float wv[8], bv[8];
        ldp8(ln2w, j8, md, wv);
        ldp8(ln2b, j8, md, bv);
        float yv[8];
#pragma unroll
        for (int ci = 0; ci < 8; ++ci) yv[ci] = (v[ci] - mu) * rs * wv[ci] + bv[ci];
        *(uint4*)&ys[tok * 72 + j8] = pk_bf8(yv);
    }
    __syncthreads();

    // MLP1 + exact GELU -> hs bf16
    {
        f32x4 ma[2];
        ma[0] = (f32x4){0.f,0.f,0.f,0.f}; ma[1] = (f32x4){0.f,0.f,0.f,0.f};
#pragma unroll
        for (int kt = 0; kt < 2; ++kt) {
            bf16x8 av = *(const bf16x8*)&ys[(mt * 16 + nl) * 72 + kt * 32 + qd * 8];
            bf16x8 b0 = *(const bf16x8*)(ff1s + o0 * 64 + kt * 32 + qd * 8);
            bf16x8 b1 = *(const bf16x8*)(ff1s + o1 * 64 + kt * 32 + qd * 8);
            ma[0] = __builtin_amdgcn_mfma_f32_16x16x32_bf16(av, b0, ma[0], 0, 0, 0);
            ma[1] = __builtin_amdgcn_mfma_f32_16x16x32_bf16(av, b1, ma[1], 0, 0, 0);
        }
        float f1b0 = ldp(ff1b, o0, md), f1b1 = ldp(ff1b, o1, md);
#pragma unroll
        for (int j = 0; j < 2; ++j)
#pragma unroll
            for (int r2 = 0; r2 < 4; ++r2) {
                int m = mt * 16 + qd * 4 + r2;
                float v = ma[j][r2] + (j ? f1b1 : f1b0);
                float g = 0.5f * v * (1.f + erff(v * 0.70710678118654752f));
                hs[m * 72 + (j ? o1 : o0)] = (short)f2bfu(g);
            }
    }
    __syncthreads();

    // MLP2 + residual into ts
    {
        f32x4 fa[2];
        fa[0] = (f32x4){0.f,0.f,0.f,0.f}; fa[1] = (f32x4){0.f,0.f,0.f,0.f};
#pragma unroll
        for (int kt = 0; kt < 2; ++kt) {
            bf16x8 av = *(const bf16x8*)&hs[(mt * 16 + nl) * 72 + kt * 32 + qd * 8];
            bf16x8 b0 = *(const bf16x8*)(ff2s + o0 * 64 + kt * 32 + qd * 8);
            bf16x8 b1 = *(const bf16x8*)(ff2s + o1 * 64 + kt * 32 + qd * 8);
            fa[0] = __builtin_amdgcn_mfma_f32_16x16x32_bf16(av, b0, fa[0], 0, 0, 0);
            fa[1] = __builtin_amdgcn_mfma_f32_16x16x32_bf16(av, b1, fa[1], 0, 0, 0);
        }
        float f2b0 = ldp(ff2b, o0, md), f2b1 = ldp(ff2b, o1, md);
#pragma unroll
        for (int j = 0; j < 2; ++j)
#pragma unroll
            for (int r2 = 0; r2 < 4; ++r2) {
                int m = mt * 16 + qd * 4 + r2;
                int oo = j ? o1 : o0;
                ts[m * 65 + oo] += fa[j][r2] + (j ? f2b1 : f2b0);
            }
    }
    __syncthreads();

    // final write: ch0 restore + state + optional out
    {
        float fv[8];
#pragma unroll
        for (int ci = 0; ci < 8; ++ci) {
            float v = ts[tok * 65 + j8 + ci];
            if (j8 == 0 && ci == 0) v = c0;
            fv[ci] = finz(v);
        }
        *(float4*)&xnew[idx]     = make_float4(fv[0], fv[1], fv[2], fv[3]);
        *(float4*)&xnew[idx + 4] = make_float4(fv[4], fv[5], fv[6], fv[7]);
        if (write_out) {
            if (md) {
                *(float4*)&((float*)dout)[idx]     = make_float4(fv[0], fv[1], fv[2], fv[3]);
                *(float4*)&((float*)dout)[idx + 4] = make_float4(fv[4], fv[5], fv[6], fv[7]);
            } else {
                *(uint4*)&((bf16*)dout)[idx] = pk_bf8(fv);
            }
        }
    }
}

// ---------------- launch ----------------

extern "C" void kernel_launch(void* const* d_in, const int* in_sizes, int n_in,
                              void* d_out, int out_size, void* d_ws, size_t ws_size,
                              hipStream_t stream) {
    (void)in_sizes; (void)n_in; (void)out_size; (void)ws_size;
    const void* x     = d_in[0];
    const void* masks = d_in[1];
    const void* p0w   = d_in[2];
    const void* p0b   = d_in[3];
    const void* p1w   = d_in[4];
    const void* p1b   = d_in[5];
    const void* fc0w  = d_in[6];
    const void* fc0b  = d_in[7];
    const void* fc1w  = d_in[8];
    const void* n0w   = d_in[9];
    const void* n0b   = d_in[10];
    const void* ln1w  = d_in[11];
    const void* ln1b  = d_in[12];
    const void* qkvw  = d_in[13];
    const void* outw  = d_in[14];
    const void* outb  = d_in[15];
    const void* ln2w  = d_in[16];
    const void* ln2b  = d_in[17];
    const void* ff1w  = d_in[18];
    const void* ff1b  = d_in[19];
    const void* ff2w  = d_in[20];
    const void* ff2b  = d_in[21];

    // workspace layout ~40.1 MB
    char* wsb = (char*)d_ws;
    float* xst0   = (float*)(wsb + 0);           //  8,388,608 B
    float* xst1   = (float*)(wsb + 8388608);     //  8,388,608 B
    float* t1buf  = (float*)(wsb + 16777216);    //  8,388,608 B
    bf16*  qkvb   = (bf16*) (wsb + 25165824);    // 12,582,912 B
    short* cw     = (short*)(wsb + 37748736);    //    147,456 B
    short* packs  = (short*)(wsb + 37896192);    //     65,536 B
    float* hbias  = (float*)(wsb + 37961728);    //        512 B
    float* wsumb  = (float*)(wsb + 37962240);    //  1,048,576 B
    float* bconb  = (float*)(wsb + 39010816);    //  1,048,576 B
    float* accv   = (float*)(wsb + 40059392);    //        384 B
    int*   mflags = (int*)  (wsb + 40059776);    //         16 B

    short* fc1s = packs;            //  8192 bf16 [64][128]
    short* qkvs = packs + 8192;     // 12288 bf16 [192][64]
    short* outs = packs + 20480;    //  4096 bf16 [64][64]
    short* ff1s = packs + 24576;    //  4096
    short* ff2s = packs + 28672;    //  4096

    k_detect<<<1, 256, 0, stream>>>((const uint4*)masks, (const uint4*)x, mflags, accv);
    k_prep<<<2465, 256, 0, stream>>>(x, xst0, p0w, p1w, p0b, p1b, fc0w, fc0b,
                                     fc1w, qkvw, outw, ff1w, ff2w,
                                     cw, packs, hbias, n0w, n0b, wsumb, bconb, mflags);

    float* xbuf[2] = {xst0, xst1};
    for (int s = 0; s < NSTEP; ++s) {
        float* cur = xbuf[s & 1];
        float* nxt = xbuf[(s + 1) & 1];
        k_perceive<<<512, 512, 0, stream>>>(cur, cw, fc1s, hbias, n0w, mflags,
                                            t1buf, accv, s);
        k_upd<<<512, 512, 0, stream>>>(cur, nxt, t1buf, wsumb, bconb, masks,
                                       qkvs, ln1w, ln1b, mflags, accv, qkvb, s);
        k_attn_ff<<<512, 512, 0, stream>>>(qkvb, cur, nxt, outs, ff1s, ff2s,
                                           outb, ln2w, ln2b, ff1b, ff2b, mflags,
                                           d_out, (s == NSTEP - 1) ? 1 : 0);
    }
}